// Round 1
// baseline (1748.314 us; speedup 1.0000x reference)
//
#include <hip/hip_runtime.h>
#include <cmath>

#define NN 1024
#define BB 64
#define WD 64
#define RR 4

constexpr float EPSF = 1e-6f;

// ---------------- device helpers ----------------
__device__ __forceinline__ float softplusf(float x) {
    return fmaxf(x, 0.f) + log1pf(expf(-fabsf(x)));
}

// block = 1024 threads (16 waves)
__device__ __forceinline__ float block_sum(float v, float* red, float* bc) {
#pragma unroll
    for (int o = 1; o < 64; o <<= 1) v += __shfl_xor(v, o, 64);
    const int wid = threadIdx.x >> 6, lane = threadIdx.x & 63;
    if (lane == 0) red[wid] = v;
    __syncthreads();
    if (wid == 0) {
        float x = (lane < 16) ? red[lane] : 0.f;
#pragma unroll
        for (int o = 1; o < 16; o <<= 1) x += __shfl_xor(x, o, 64);
        if (lane == 0) bc[0] = x;
    }
    __syncthreads();
    return bc[0];
}

__device__ __forceinline__ float block_max(float v, float* red, float* bc) {
#pragma unroll
    for (int o = 1; o < 64; o <<= 1) v = fmaxf(v, __shfl_xor(v, o, 64));
    const int wid = threadIdx.x >> 6, lane = threadIdx.x & 63;
    if (lane == 0) red[wid] = v;
    __syncthreads();
    if (wid == 0) {
        float x = (lane < 16) ? red[lane] : -INFINITY;
#pragma unroll
        for (int o = 1; o < 16; o <<= 1) x = fmaxf(x, __shfl_xor(x, o, 64));
        if (lane == 0) bc[0] = x;
    }
    __syncthreads();
    return bc[0];
}

__device__ __forceinline__ float4 block_sum4(float4 v, float4* red, float4* bc) {
#pragma unroll
    for (int o = 1; o < 64; o <<= 1) {
        v.x += __shfl_xor(v.x, o, 64); v.y += __shfl_xor(v.y, o, 64);
        v.z += __shfl_xor(v.z, o, 64); v.w += __shfl_xor(v.w, o, 64);
    }
    const int wid = threadIdx.x >> 6, lane = threadIdx.x & 63;
    if (lane == 0) red[wid] = v;
    __syncthreads();
    if (wid == 0) {
        float4 x;
        if (lane < 16) x = red[lane];
        else { x.x = 0.f; x.y = 0.f; x.z = 0.f; x.w = 0.f; }
#pragma unroll
        for (int o = 1; o < 16; o <<= 1) {
            x.x += __shfl_xor(x.x, o, 64); x.y += __shfl_xor(x.y, o, 64);
            x.z += __shfl_xor(x.z, o, 64); x.w += __shfl_xor(x.w, o, 64);
        }
        if (lane == 0) bc[0] = x;
    }
    __syncthreads();
    return bc[0];
}

__device__ __forceinline__ float4 block_max4(float4 v, float4* red, float4* bc) {
#pragma unroll
    for (int o = 1; o < 64; o <<= 1) {
        v.x = fmaxf(v.x, __shfl_xor(v.x, o, 64)); v.y = fmaxf(v.y, __shfl_xor(v.y, o, 64));
        v.z = fmaxf(v.z, __shfl_xor(v.z, o, 64)); v.w = fmaxf(v.w, __shfl_xor(v.w, o, 64));
    }
    const int wid = threadIdx.x >> 6, lane = threadIdx.x & 63;
    if (lane == 0) red[wid] = v;
    __syncthreads();
    if (wid == 0) {
        float4 x;
        if (lane < 16) x = red[lane];
        else { x.x = -INFINITY; x.y = -INFINITY; x.z = -INFINITY; x.w = -INFINITY; }
#pragma unroll
        for (int o = 1; o < 16; o <<= 1) {
            x.x = fmaxf(x.x, __shfl_xor(x.x, o, 64)); x.y = fmaxf(x.y, __shfl_xor(x.y, o, 64));
            x.z = fmaxf(x.z, __shfl_xor(x.z, o, 64)); x.w = fmaxf(x.w, __shfl_xor(x.w, o, 64));
        }
        if (lane == 0) bc[0] = x;
    }
    __syncthreads();
    return bc[0];
}

// ---------------- K1: per-batch prep ----------------
// usage/phi -> write_content softmax -> allocation (bitonic sort + prod scan)
// -> write_weights -> read_content (vs recomputed memory_new) -> S_rp / S_uww
// Also emits uwG[b,r,n] = prw[b,r,n] * ww[b,n] so link_kernel skips the multiply.
__global__ __launch_bounds__(1024) void prep_kernel(
    const float* __restrict__ memory, const float* __restrict__ prw,
    const float* __restrict__ pww, const float* __restrict__ pusage,
    const float* __restrict__ pprec,
    const float* __restrict__ rkeys_g, const float* __restrict__ rstr_g,
    const float* __restrict__ wkeys_g, const float* __restrict__ wstr_g,
    const float* __restrict__ wvec_g, const float* __restrict__ evec_g,
    const float* __restrict__ fg_g, const float* __restrict__ ag_g,
    const float* __restrict__ wg_g,
    float* __restrict__ wwG, float* __restrict__ uwG, float* __restrict__ rcG,
    float* __restrict__ SrpG, float* __restrict__ SuwwG)
{
    __shared__ float wkey[WD], wvecS[WD], evecS[WD], rkey[RR * WD];
    __shared__ float skey[NN];
    __shared__ int   sidx[NN];
    __shared__ float pArr[NN], wcArr[NN], allocArr[NN];
    __shared__ float red1[16], bc1[1];
    __shared__ float4 red4[16], bc4[1];

    const int b = blockIdx.x, tid = threadIdx.x, n = tid;

    if (tid < WD) {
        wkey[tid]  = wkeys_g[b * WD + tid];
        wvecS[tid] = wvec_g[b * WD + tid];
        evecS[tid] = evec_g[b * WD + tid];
    } else if (tid >= 128 && tid < 128 + RR * WD) {
        int k = tid - 128;
        rkey[k] = rkeys_g[b * RR * WD + k];
    }
    __syncthreads();

    // ---- usage after free gates ----
    float ur[RR];
#pragma unroll
    for (int r = 0; r < RR; ++r) ur[r] = prw[((size_t)b * RR + r) * NN + n];
    const float pw = pww[b * NN + n];
    const float pu = pusage[b * NN + n];
    float usage = pu + (1.f - pu) * pw;
    float phi = 1.f;
#pragma unroll
    for (int r = 0; r < RR; ++r) phi *= (1.f - fg_g[b * RR + r] * ur[r]);
    usage *= phi;

    // ---- write content weights (cosine + softmax) ----
    const float* mrow = memory + ((size_t)b * NN + n) * WD;
    float dot = 0.f, nrm = 0.f, knrm = 0.f;
#pragma unroll 4
    for (int w4 = 0; w4 < WD / 4; ++w4) {
        const float4 m = *(const float4*)(mrow + w4 * 4);
        const float4 k = *(const float4*)(wkey + w4 * 4);
        dot  += m.x * k.x + m.y * k.y + m.z * k.z + m.w * k.w;
        nrm  += m.x * m.x + m.y * m.y + m.z * m.z + m.w * m.w;
        knrm += k.x * k.x + k.y * k.y + k.z * k.z + k.w * k.w;
    }
    const float sim = dot / (sqrtf(knrm + EPSF) * sqrtf(nrm + EPSF) + EPSF);
    const float sharp = sim * softplusf(wstr_g[b]);
    const float mxw = block_max(sharp, red1, bc1);
    const float exw = expf(sharp - mxw);
    const float smw = block_sum(exw, red1, bc1);
    wcArr[n] = exw / smw;

    // ---- allocation: stable descending sort of nonusage ----
    const float ue = EPSF + (1.f - EPSF) * usage;
    skey[n] = 1.f - ue;
    sidx[n] = n;
    __syncthreads();
    for (int k = 2; k <= NN; k <<= 1) {
        for (int j = k >> 1; j > 0; j >>= 1) {
            const int ixj = tid ^ j;
            if (ixj > tid) {
                const float ka = skey[tid], kb = skey[ixj];
                const int ia = sidx[tid], ib = sidx[ixj];
                const bool precBA = (kb > ka) || (kb == ka && ib < ia);
                const bool precAB = (ka > kb) || (ka == kb && ia < ib);
                const bool dosw = ((tid & k) == 0) ? precBA : precAB;
                if (dosw) { skey[tid] = kb; skey[ixj] = ka; sidx[tid] = ib; sidx[ixj] = ia; }
            }
            __syncthreads();
        }
    }
    // exclusive product scan of sorted usage
    pArr[n] = (n == 0) ? 1.f : (1.f - skey[n - 1]);
    __syncthreads();
    for (int off = 1; off < NN; off <<= 1) {
        const float t = (n >= off) ? pArr[n - off] : 1.f;
        __syncthreads();
        pArr[n] *= t;
        __syncthreads();
    }
    allocArr[sidx[n]] = skey[n] * pArr[n];
    __syncthreads();

    const float agv = ag_g[b], wgv = wg_g[b];
    const float ww = wgv * (agv * allocArr[n] + (1.f - agv) * wcArr[n]);
    wwG[b * NN + n] = ww;
#pragma unroll
    for (int r = 0; r < RR; ++r)
        uwG[((size_t)b * RR + r) * NN + n] = ur[r] * ww;

    // ---- read content weights vs memory_new (recomputed inline) ----
    float rdot0 = 0, rdot1 = 0, rdot2 = 0, rdot3 = 0, nn2 = 0;
    float rk0 = 0, rk1 = 0, rk2 = 0, rk3 = 0;
#pragma unroll 4
    for (int w4 = 0; w4 < WD / 4; ++w4) {
        const float4 m = *(const float4*)(mrow + w4 * 4);
        const float4 e = *(const float4*)(evecS + w4 * 4);
        const float4 v = *(const float4*)(wvecS + w4 * 4);
        float4 mn_;
        mn_.x = m.x * (1.f - ww * e.x) + ww * v.x;
        mn_.y = m.y * (1.f - ww * e.y) + ww * v.y;
        mn_.z = m.z * (1.f - ww * e.z) + ww * v.z;
        mn_.w = m.w * (1.f - ww * e.w) + ww * v.w;
        nn2 += mn_.x * mn_.x + mn_.y * mn_.y + mn_.z * mn_.z + mn_.w * mn_.w;
        const float4 k0 = *(const float4*)(rkey + 0 * WD + w4 * 4);
        const float4 k1 = *(const float4*)(rkey + 1 * WD + w4 * 4);
        const float4 k2 = *(const float4*)(rkey + 2 * WD + w4 * 4);
        const float4 k3 = *(const float4*)(rkey + 3 * WD + w4 * 4);
        rdot0 += k0.x * mn_.x + k0.y * mn_.y + k0.z * mn_.z + k0.w * mn_.w;
        rdot1 += k1.x * mn_.x + k1.y * mn_.y + k1.z * mn_.z + k1.w * mn_.w;
        rdot2 += k2.x * mn_.x + k2.y * mn_.y + k2.z * mn_.z + k2.w * mn_.w;
        rdot3 += k3.x * mn_.x + k3.y * mn_.y + k3.z * mn_.z + k3.w * mn_.w;
        rk0 += k0.x * k0.x + k0.y * k0.y + k0.z * k0.z + k0.w * k0.w;
        rk1 += k1.x * k1.x + k1.y * k1.y + k1.z * k1.z + k1.w * k1.w;
        rk2 += k2.x * k2.x + k2.y * k2.y + k2.z * k2.z + k2.w * k2.w;
        rk3 += k3.x * k3.x + k3.y * k3.y + k3.z * k3.z + k3.w * k3.w;
    }
    const float mnn = sqrtf(nn2 + EPSF);
    float4 sharp4;
    sharp4.x = rdot0 / (sqrtf(rk0 + EPSF) * mnn + EPSF) * softplusf(rstr_g[b * RR + 0]);
    sharp4.y = rdot1 / (sqrtf(rk1 + EPSF) * mnn + EPSF) * softplusf(rstr_g[b * RR + 1]);
    sharp4.z = rdot2 / (sqrtf(rk2 + EPSF) * mnn + EPSF) * softplusf(rstr_g[b * RR + 2]);
    sharp4.w = rdot3 / (sqrtf(rk3 + EPSF) * mnn + EPSF) * softplusf(rstr_g[b * RR + 3]);
    const float4 mx4 = block_max4(sharp4, red4, bc4);
    float4 e4;
    e4.x = expf(sharp4.x - mx4.x); e4.y = expf(sharp4.y - mx4.y);
    e4.z = expf(sharp4.z - mx4.z); e4.w = expf(sharp4.w - mx4.w);
    const float4 s4 = block_sum4(e4, red4, bc4);
    rcG[((size_t)b * RR + 0) * NN + n] = e4.x / s4.x;
    rcG[((size_t)b * RR + 1) * NN + n] = e4.y / s4.y;
    rcG[((size_t)b * RR + 2) * NN + n] = e4.z / s4.z;
    rcG[((size_t)b * RR + 3) * NN + n] = e4.w / s4.w;

    // ---- scalar sums S_rp, S_uww ----
    const float prec_n = pprec[b * NN + n];
    float4 sp4, sw4;
    sp4.x = ur[0] * prec_n; sp4.y = ur[1] * prec_n; sp4.z = ur[2] * prec_n; sp4.w = ur[3] * prec_n;
    const float4 SrpV = block_sum4(sp4, red4, bc4);
    sw4.x = ur[0] * ww; sw4.y = ur[1] * ww; sw4.z = ur[2] * ww; sw4.w = ur[3] * ww;
    const float4 SuwwV = block_sum4(sw4, red4, bc4);
    if (tid == 0) {
        SrpG[b * RR + 0] = SrpV.x; SrpG[b * RR + 1] = SrpV.y;
        SrpG[b * RR + 2] = SrpV.z; SrpG[b * RR + 3] = SrpV.w;
        SuwwG[b * RR + 0] = SuwwV.x; SuwwG[b * RR + 1] = SuwwV.y;
        SuwwG[b * RR + 2] = SuwwV.z; SuwwG[b * RR + 3] = SuwwV.w;
    }
}

// ---------------- K2: one pass over prev_link (256 MB) ----------------
// Block = 256 threads (4 waves, wave w handles r=w); covers 64 rows x 256 cols.
// grid.x = 64: stripe = bx>>2 (rows n0=stripe*64), mq = bx&3 (cols mBase=mq*256).
// 4 tiles of 64x64 per block, register-double-buffered staging.
// Row pass: lane <-> row, b128 tile reads, wave-uniform u broadcasts.
// Col pass: b128 over 4 cols x 4-row groups (q=lane>>4), shfl_xor(16,32) reduce.
// All outputs accumulated with atomics (rowU..colV zeroed by memset).
__global__ __launch_bounds__(256, 4) void link_kernel(
    const float* __restrict__ L, const float* __restrict__ uG,
    const float* __restrict__ uwG,
    float* __restrict__ rowU, float* __restrict__ rowV,
    float* __restrict__ colU, float* __restrict__ colV)
{
    __shared__ float uRow[RR * 256];   // u[r][mBase..mBase+255]
    __shared__ float uwRow[RR * 256];
    __shared__ float uCol[RR * 64];    // u[r][n0..n0+63]
    __shared__ float uwCol[RR * 64];
    __shared__ float tile[64 * 68];    // pad 68: b128-friendly bank spread

    const int b = blockIdx.y;
    const int bx = blockIdx.x;
    const int n0 = (bx >> 2) * 64;
    const int mBase = (bx & 3) * 256;
    const int t = threadIdx.x;
    const int lane = t & 63;
    const int wid = t >> 6;            // = r

    // stage u/uw slices (visible after first barrier)
#pragma unroll
    for (int k = 0; k < 4; ++k) {
        const int kk = t + (k << 8);
        const int r = kk >> 8, m = kk & 255;
        const size_t gi = ((size_t)b * RR + r) * NN + mBase + m;
        uRow[kk]  = uG[gi];
        uwRow[kk] = uwG[gi];
    }
    {
        const int r = t >> 6, i = t & 63;
        const size_t gi = ((size_t)b * RR + r) * NN + n0 + i;
        uCol[t]  = uG[gi];
        uwCol[t] = uwG[gi];
    }

    const float* Lb = L + (size_t)b * NN * NN + (size_t)n0 * NN + mBase;
    const int srow = t >> 4;           // staging rows: srow, +16, +32, +48
    const int sc4  = (t & 15) << 2;    // staging col (floats) within tile

    // prologue: tile 0 -> regs -> LDS
    float4 pre[4];
#pragma unroll
    for (int k = 0; k < 4; ++k)
        pre[k] = *(const float4*)&Lb[(size_t)(srow + (k << 4)) * NN + sc4];
#pragma unroll
    for (int k = 0; k < 4; ++k)
        *(float4*)&tile[(srow + (k << 4)) * 68 + sc4] = pre[k];

    float fuA = 0.f, fvA = 0.f;
    const int q = lane >> 4;
    const int c16 = (lane & 15) << 2;

#pragma unroll
    for (int tt = 0; tt < 4; ++tt) {
        __syncthreads();               // tile tt (and u slices at tt==0) visible
        if (tt < 3) {                  // prefetch next tile into regs (latency hides under compute)
#pragma unroll
            for (int k = 0; k < 4; ++k)
                pre[k] = *(const float4*)&Lb[(size_t)(srow + (k << 4)) * NN + ((tt + 1) << 6) + sc4];
        }

        // ---- row pass: lane <-> row (n0+lane) ----
#pragma unroll
        for (int g = 0; g < 16; ++g) {
            const float4 v  = *(const float4*)&tile[lane * 68 + (g << 2)];
            const float4 u  = *(const float4*)&uRow[(wid << 8) + (tt << 6) + (g << 2)];
            const float4 uw = *(const float4*)&uwRow[(wid << 8) + (tt << 6) + (g << 2)];
            fuA += v.x * u.x + v.y * u.y + v.z * u.z + v.w * u.w;
            fvA += v.x * uw.x + v.y * uw.y + v.z * uw.z + v.w * uw.w;
        }

        // ---- col pass: lane -> 4 cols (c16..c16+3), row group q; b128 reads ----
        float4 cu4 = {0.f, 0.f, 0.f, 0.f}, cv4 = {0.f, 0.f, 0.f, 0.f};
#pragma unroll
        for (int n4 = 0; n4 < 16; ++n4) {
            const int row = (n4 << 2) + q;
            const float4 v = *(const float4*)&tile[row * 68 + c16];
            const float uv  = uCol[(wid << 6) + row];
            const float uwv = uwCol[(wid << 6) + row];
            cu4.x += uv * v.x;  cu4.y += uv * v.y;  cu4.z += uv * v.z;  cu4.w += uv * v.w;
            cv4.x += uwv * v.x; cv4.y += uwv * v.y; cv4.z += uwv * v.z; cv4.w += uwv * v.w;
        }
        // merge the 4 q-groups (lanes differing in bits 4 and 5)
#pragma unroll
        for (int off = 16; off < 64; off <<= 1) {
            cu4.x += __shfl_xor(cu4.x, off, 64); cu4.y += __shfl_xor(cu4.y, off, 64);
            cu4.z += __shfl_xor(cu4.z, off, 64); cu4.w += __shfl_xor(cu4.w, off, 64);
            cv4.x += __shfl_xor(cv4.x, off, 64); cv4.y += __shfl_xor(cv4.y, off, 64);
            cv4.z += __shfl_xor(cv4.z, off, 64); cv4.w += __shfl_xor(cv4.w, off, 64);
        }
        if (lane < 16) {
            const size_t cb = ((size_t)b * RR + wid) * NN + mBase + (tt << 6) + (lane << 2);
            unsafeAtomicAdd(&colU[cb + 0], cu4.x);
            unsafeAtomicAdd(&colU[cb + 1], cu4.y);
            unsafeAtomicAdd(&colU[cb + 2], cu4.z);
            unsafeAtomicAdd(&colU[cb + 3], cu4.w);
            unsafeAtomicAdd(&colV[cb + 0], cv4.x);
            unsafeAtomicAdd(&colV[cb + 1], cv4.y);
            unsafeAtomicAdd(&colV[cb + 2], cv4.z);
            unsafeAtomicAdd(&colV[cb + 3], cv4.w);
        }

        __syncthreads();               // everyone done reading tile tt
        if (tt < 3) {
#pragma unroll
            for (int k = 0; k < 4; ++k)
                *(float4*)&tile[(srow + (k << 4)) * 68 + sc4] = pre[k];
        }
    }
    unsafeAtomicAdd(&rowU[((size_t)b * RR + wid) * NN + n0 + lane], fuA);
    unsafeAtomicAdd(&rowV[((size_t)b * RR + wid) * NN + n0 + lane], fvA);
}

// ---------------- K3: assemble read weights + read_words ----------------
// grid (16, BB): 64-row chunks; r folded into threads (t>>6) for phase 1.
__global__ __launch_bounds__(256) void combine_kernel(
    const float* __restrict__ memory, const float* __restrict__ prw,
    const float* __restrict__ pprec, const float* __restrict__ L,
    const float* __restrict__ evec_g, const float* __restrict__ wvec_g,
    const float* __restrict__ rmode_g,
    const float* __restrict__ wwG, const float* __restrict__ rcG,
    const float* __restrict__ rowU, const float* __restrict__ rowV,
    const float* __restrict__ colU, const float* __restrict__ colV,
    const float* __restrict__ SrpG, const float* __restrict__ SuwwG,
    float* __restrict__ out)
{
    __shared__ float rwL[RR][64];
    __shared__ float wwS[64];

    const int b = blockIdx.y;
    const int n0 = blockIdx.x * 64;
    const int t = threadIdx.x;
    const int r = t >> 6, i = t & 63;
    const int n = n0 + i;

    const float wwn = wwG[b * NN + n];
    if (r == 0) wwS[i] = wwn;
    const float prec_n = pprec[b * NN + n];
    const float diag = L[(size_t)b * NN * NN + (size_t)n * (NN + 1)];

    {
        const size_t idx = ((size_t)b * RR + r) * NN + n;
        const float un = prw[idx];
        const float rc = rcG[idx];
        const float ru = rowU[idx], rv = rowV[idx];
        const float cuv = colU[idx], cvv = colV[idx];
        const float Srp = SrpG[b * RR + r], Suww = SuwwG[b * RR + r];
        const float corr = un * (1.f - 2.f * wwn) * diag;
        const float fwd = (1.f - wwn) * ru - rv - corr + wwn * (Srp - un * prec_n);
        const float bwd = (1.f - wwn) * cuv - cvv - corr + prec_n * (Suww - un * wwn);
        const float m0 = rmode_g[((size_t)b * RR + r) * 3 + 0];
        const float m1 = rmode_g[((size_t)b * RR + r) * 3 + 1];
        const float m2 = rmode_g[((size_t)b * RR + r) * 3 + 2];
        const float mx = fmaxf(m0, fmaxf(m1, m2));
        const float e0 = expf(m0 - mx), e1 = expf(m1 - mx), e2 = expf(m2 - mx);
        const float inv = 1.f / (e0 + e1 + e2);
        // mode[...,0]=backward, [...,1]=forward, [...,2]=content
        rwL[r][i] = (e2 * inv) * rc + (e1 * inv) * fwd + (e0 * inv) * bwd;
    }
    __syncthreads();

    // partial read_words over this 64-row chunk; wave r handles read head r, lane = w
    const int w = i;
    const float ev = evec_g[b * WD + w], wv = wvec_g[b * WD + w];
    float acc = 0.f;
    const float* mb = memory + ((size_t)b * NN + n0) * WD;
#pragma unroll 8
    for (int k = 0; k < 64; ++k) {
        const float m = mb[(size_t)k * WD + w];
        const float wwi = wwS[k];
        acc += rwL[r][k] * (m * (1.f - wwi * ev) + wwi * wv);
    }
    unsafeAtomicAdd(&out[((size_t)b * RR + r) * WD + w], acc);
}

// ---------------- launch ----------------
extern "C" void kernel_launch(void* const* d_in, const int* in_sizes, int n_in,
                              void* d_out, int out_size, void* d_ws, size_t ws_size,
                              hipStream_t stream) {
    const float* memory = (const float*)d_in[0];
    const float* prw    = (const float*)d_in[1];
    const float* pww    = (const float*)d_in[2];
    const float* pusage = (const float*)d_in[3];
    const float* plink  = (const float*)d_in[4];
    const float* pprec  = (const float*)d_in[5];
    const float* rkeys  = (const float*)d_in[6];
    const float* rstr   = (const float*)d_in[7];
    const float* wkeys  = (const float*)d_in[8];
    const float* wstr   = (const float*)d_in[9];
    const float* wvec   = (const float*)d_in[10];
    const float* evec   = (const float*)d_in[11];
    const float* fg     = (const float*)d_in[12];
    const float* ag     = (const float*)d_in[13];
    const float* wg     = (const float*)d_in[14];
    const float* rmode  = (const float*)d_in[15];

    float* ws = (float*)d_ws;
    const size_t BN  = (size_t)BB * NN;          // 65536
    const size_t BRN = (size_t)BB * RR * NN;     // 262144
    float* wwG  = ws;
    float* rcG  = wwG + BN;
    float* uwG  = rcG + BRN;
    float* rowU = uwG + BRN;
    float* rowV = rowU + BRN;
    float* colU = rowV + BRN;
    float* colV = colU + BRN;
    float* Srp  = colV + BRN;
    float* Suww = Srp + (size_t)BB * RR;

    // zero the atomic accumulators (rowU,rowV,colU,colV contiguous) and output
    hipMemsetAsync(rowU, 0, 4 * BRN * sizeof(float), stream);
    hipMemsetAsync(d_out, 0, (size_t)out_size * sizeof(float), stream);

    prep_kernel<<<BB, 1024, 0, stream>>>(memory, prw, pww, pusage, pprec,
                                         rkeys, rstr, wkeys, wstr, wvec, evec,
                                         fg, ag, wg, wwG, uwG, rcG, Srp, Suww);
    link_kernel<<<dim3(64, BB), 256, 0, stream>>>(plink, prw, uwG,
                                                  rowU, rowV, colU, colV);
    combine_kernel<<<dim3(16, BB), 256, 0, stream>>>(memory, prw, pprec, plink,
                                                     evec, wvec, rmode,
                                                     wwG, rcG, rowU, rowV, colU, colV,
                                                     Srp, Suww, (float*)d_out);
}

// Round 2
// 558.975 us; speedup vs baseline: 3.1277x; 3.1277x over previous
//
#include <hip/hip_runtime.h>
#include <cmath>

#define NN 1024
#define BB 64
#define WD 64
#define RR 4

constexpr float EPSF = 1e-6f;

// ---------------- device helpers ----------------
__device__ __forceinline__ float softplusf(float x) {
    return fmaxf(x, 0.f) + log1pf(expf(-fabsf(x)));
}

// block = 1024 threads (16 waves)
__device__ __forceinline__ float block_sum(float v, float* red, float* bc) {
#pragma unroll
    for (int o = 1; o < 64; o <<= 1) v += __shfl_xor(v, o, 64);
    const int wid = threadIdx.x >> 6, lane = threadIdx.x & 63;
    if (lane == 0) red[wid] = v;
    __syncthreads();
    if (wid == 0) {
        float x = (lane < 16) ? red[lane] : 0.f;
#pragma unroll
        for (int o = 1; o < 16; o <<= 1) x += __shfl_xor(x, o, 64);
        if (lane == 0) bc[0] = x;
    }
    __syncthreads();
    return bc[0];
}

__device__ __forceinline__ float block_max(float v, float* red, float* bc) {
#pragma unroll
    for (int o = 1; o < 64; o <<= 1) v = fmaxf(v, __shfl_xor(v, o, 64));
    const int wid = threadIdx.x >> 6, lane = threadIdx.x & 63;
    if (lane == 0) red[wid] = v;
    __syncthreads();
    if (wid == 0) {
        float x = (lane < 16) ? red[lane] : -INFINITY;
#pragma unroll
        for (int o = 1; o < 16; o <<= 1) x = fmaxf(x, __shfl_xor(x, o, 64));
        if (lane == 0) bc[0] = x;
    }
    __syncthreads();
    return bc[0];
}

__device__ __forceinline__ float4 block_sum4(float4 v, float4* red, float4* bc) {
#pragma unroll
    for (int o = 1; o < 64; o <<= 1) {
        v.x += __shfl_xor(v.x, o, 64); v.y += __shfl_xor(v.y, o, 64);
        v.z += __shfl_xor(v.z, o, 64); v.w += __shfl_xor(v.w, o, 64);
    }
    const int wid = threadIdx.x >> 6, lane = threadIdx.x & 63;
    if (lane == 0) red[wid] = v;
    __syncthreads();
    if (wid == 0) {
        float4 x;
        if (lane < 16) x = red[lane];
        else { x.x = 0.f; x.y = 0.f; x.z = 0.f; x.w = 0.f; }
#pragma unroll
        for (int o = 1; o < 16; o <<= 1) {
            x.x += __shfl_xor(x.x, o, 64); x.y += __shfl_xor(x.y, o, 64);
            x.z += __shfl_xor(x.z, o, 64); x.w += __shfl_xor(x.w, o, 64);
        }
        if (lane == 0) bc[0] = x;
    }
    __syncthreads();
    return bc[0];
}

__device__ __forceinline__ float4 block_max4(float4 v, float4* red, float4* bc) {
#pragma unroll
    for (int o = 1; o < 64; o <<= 1) {
        v.x = fmaxf(v.x, __shfl_xor(v.x, o, 64)); v.y = fmaxf(v.y, __shfl_xor(v.y, o, 64));
        v.z = fmaxf(v.z, __shfl_xor(v.z, o, 64)); v.w = fmaxf(v.w, __shfl_xor(v.w, o, 64));
    }
    const int wid = threadIdx.x >> 6, lane = threadIdx.x & 63;
    if (lane == 0) red[wid] = v;
    __syncthreads();
    if (wid == 0) {
        float4 x;
        if (lane < 16) x = red[lane];
        else { x.x = -INFINITY; x.y = -INFINITY; x.z = -INFINITY; x.w = -INFINITY; }
#pragma unroll
        for (int o = 1; o < 16; o <<= 1) {
            x.x = fmaxf(x.x, __shfl_xor(x.x, o, 64)); x.y = fmaxf(x.y, __shfl_xor(x.y, o, 64));
            x.z = fmaxf(x.z, __shfl_xor(x.z, o, 64)); x.w = fmaxf(x.w, __shfl_xor(x.w, o, 64));
        }
        if (lane == 0) bc[0] = x;
    }
    __syncthreads();
    return bc[0];
}

// component select that folds when c is a compile-time constant
#define COMP4(v4, c) ((c) == 0 ? (v4).x : ((c) == 1 ? (v4).y : ((c) == 2 ? (v4).z : (v4).w)))

// ---------------- K1: per-batch prep ----------------
// usage/phi -> write_content softmax -> allocation (bitonic sort + prod scan)
// -> write_weights -> read_content (vs recomputed memory_new) -> S_rp / S_uww
// Also emits uwG[b,r,n] = prw[b,r,n] * ww[b,n] so link_kernel skips the multiply.
__global__ __launch_bounds__(1024) void prep_kernel(
    const float* __restrict__ memory, const float* __restrict__ prw,
    const float* __restrict__ pww, const float* __restrict__ pusage,
    const float* __restrict__ pprec,
    const float* __restrict__ rkeys_g, const float* __restrict__ rstr_g,
    const float* __restrict__ wkeys_g, const float* __restrict__ wstr_g,
    const float* __restrict__ wvec_g, const float* __restrict__ evec_g,
    const float* __restrict__ fg_g, const float* __restrict__ ag_g,
    const float* __restrict__ wg_g,
    float* __restrict__ wwG, float* __restrict__ uwG, float* __restrict__ rcG,
    float* __restrict__ SrpG, float* __restrict__ SuwwG)
{
    __shared__ float wkey[WD], wvecS[WD], evecS[WD], rkey[RR * WD];
    __shared__ float skey[NN];
    __shared__ int   sidx[NN];
    __shared__ float pArr[NN], wcArr[NN], allocArr[NN];
    __shared__ float red1[16], bc1[1];
    __shared__ float4 red4[16], bc4[1];

    const int b = blockIdx.x, tid = threadIdx.x, n = tid;

    if (tid < WD) {
        wkey[tid]  = wkeys_g[b * WD + tid];
        wvecS[tid] = wvec_g[b * WD + tid];
        evecS[tid] = evec_g[b * WD + tid];
    } else if (tid >= 128 && tid < 128 + RR * WD) {
        int k = tid - 128;
        rkey[k] = rkeys_g[b * RR * WD + k];
    }
    __syncthreads();

    // ---- usage after free gates ----
    float ur[RR];
#pragma unroll
    for (int r = 0; r < RR; ++r) ur[r] = prw[((size_t)b * RR + r) * NN + n];
    const float pw = pww[b * NN + n];
    const float pu = pusage[b * NN + n];
    float usage = pu + (1.f - pu) * pw;
    float phi = 1.f;
#pragma unroll
    for (int r = 0; r < RR; ++r) phi *= (1.f - fg_g[b * RR + r] * ur[r]);
    usage *= phi;

    // ---- write content weights (cosine + softmax) ----
    const float* mrow = memory + ((size_t)b * NN + n) * WD;
    float dot = 0.f, nrm = 0.f, knrm = 0.f;
#pragma unroll 4
    for (int w4 = 0; w4 < WD / 4; ++w4) {
        const float4 m = *(const float4*)(mrow + w4 * 4);
        const float4 k = *(const float4*)(wkey + w4 * 4);
        dot  += m.x * k.x + m.y * k.y + m.z * k.z + m.w * k.w;
        nrm  += m.x * m.x + m.y * m.y + m.z * m.z + m.w * m.w;
        knrm += k.x * k.x + k.y * k.y + k.z * k.z + k.w * k.w;
    }
    const float sim = dot / (sqrtf(knrm + EPSF) * sqrtf(nrm + EPSF) + EPSF);
    const float sharp = sim * softplusf(wstr_g[b]);
    const float mxw = block_max(sharp, red1, bc1);
    const float exw = expf(sharp - mxw);
    const float smw = block_sum(exw, red1, bc1);
    wcArr[n] = exw / smw;

    // ---- allocation: stable descending sort of nonusage ----
    const float ue = EPSF + (1.f - EPSF) * usage;
    skey[n] = 1.f - ue;
    sidx[n] = n;
    __syncthreads();
    for (int k = 2; k <= NN; k <<= 1) {
        for (int j = k >> 1; j > 0; j >>= 1) {
            const int ixj = tid ^ j;
            if (ixj > tid) {
                const float ka = skey[tid], kb = skey[ixj];
                const int ia = sidx[tid], ib = sidx[ixj];
                const bool precBA = (kb > ka) || (kb == ka && ib < ia);
                const bool precAB = (ka > kb) || (ka == kb && ia < ib);
                const bool dosw = ((tid & k) == 0) ? precBA : precAB;
                if (dosw) { skey[tid] = kb; skey[ixj] = ka; sidx[tid] = ib; sidx[ixj] = ia; }
            }
            __syncthreads();
        }
    }
    // exclusive product scan of sorted usage
    pArr[n] = (n == 0) ? 1.f : (1.f - skey[n - 1]);
    __syncthreads();
    for (int off = 1; off < NN; off <<= 1) {
        const float t = (n >= off) ? pArr[n - off] : 1.f;
        __syncthreads();
        pArr[n] *= t;
        __syncthreads();
    }
    allocArr[sidx[n]] = skey[n] * pArr[n];
    __syncthreads();

    const float agv = ag_g[b], wgv = wg_g[b];
    const float ww = wgv * (agv * allocArr[n] + (1.f - agv) * wcArr[n]);
    wwG[b * NN + n] = ww;
#pragma unroll
    for (int r = 0; r < RR; ++r)
        uwG[((size_t)b * RR + r) * NN + n] = ur[r] * ww;

    // ---- read content weights vs memory_new (recomputed inline) ----
    float rdot0 = 0, rdot1 = 0, rdot2 = 0, rdot3 = 0, nn2 = 0;
    float rk0 = 0, rk1 = 0, rk2 = 0, rk3 = 0;
#pragma unroll 4
    for (int w4 = 0; w4 < WD / 4; ++w4) {
        const float4 m = *(const float4*)(mrow + w4 * 4);
        const float4 e = *(const float4*)(evecS + w4 * 4);
        const float4 v = *(const float4*)(wvecS + w4 * 4);
        float4 mn_;
        mn_.x = m.x * (1.f - ww * e.x) + ww * v.x;
        mn_.y = m.y * (1.f - ww * e.y) + ww * v.y;
        mn_.z = m.z * (1.f - ww * e.z) + ww * v.z;
        mn_.w = m.w * (1.f - ww * e.w) + ww * v.w;
        nn2 += mn_.x * mn_.x + mn_.y * mn_.y + mn_.z * mn_.z + mn_.w * mn_.w;
        const float4 k0 = *(const float4*)(rkey + 0 * WD + w4 * 4);
        const float4 k1 = *(const float4*)(rkey + 1 * WD + w4 * 4);
        const float4 k2 = *(const float4*)(rkey + 2 * WD + w4 * 4);
        const float4 k3 = *(const float4*)(rkey + 3 * WD + w4 * 4);
        rdot0 += k0.x * mn_.x + k0.y * mn_.y + k0.z * mn_.z + k0.w * mn_.w;
        rdot1 += k1.x * mn_.x + k1.y * mn_.y + k1.z * mn_.z + k1.w * mn_.w;
        rdot2 += k2.x * mn_.x + k2.y * mn_.y + k2.z * mn_.z + k2.w * mn_.w;
        rdot3 += k3.x * mn_.x + k3.y * mn_.y + k3.z * mn_.z + k3.w * mn_.w;
        rk0 += k0.x * k0.x + k0.y * k0.y + k0.z * k0.z + k0.w * k0.w;
        rk1 += k1.x * k1.x + k1.y * k1.y + k1.z * k1.z + k1.w * k1.w;
        rk2 += k2.x * k2.x + k2.y * k2.y + k2.z * k2.z + k2.w * k2.w;
        rk3 += k3.x * k3.x + k3.y * k3.y + k3.z * k3.z + k3.w * k3.w;
    }
    const float mnn = sqrtf(nn2 + EPSF);
    float4 sharp4;
    sharp4.x = rdot0 / (sqrtf(rk0 + EPSF) * mnn + EPSF) * softplusf(rstr_g[b * RR + 0]);
    sharp4.y = rdot1 / (sqrtf(rk1 + EPSF) * mnn + EPSF) * softplusf(rstr_g[b * RR + 1]);
    sharp4.z = rdot2 / (sqrtf(rk2 + EPSF) * mnn + EPSF) * softplusf(rstr_g[b * RR + 2]);
    sharp4.w = rdot3 / (sqrtf(rk3 + EPSF) * mnn + EPSF) * softplusf(rstr_g[b * RR + 3]);
    const float4 mx4 = block_max4(sharp4, red4, bc4);
    float4 e4;
    e4.x = expf(sharp4.x - mx4.x); e4.y = expf(sharp4.y - mx4.y);
    e4.z = expf(sharp4.z - mx4.z); e4.w = expf(sharp4.w - mx4.w);
    const float4 s4 = block_sum4(e4, red4, bc4);
    rcG[((size_t)b * RR + 0) * NN + n] = e4.x / s4.x;
    rcG[((size_t)b * RR + 1) * NN + n] = e4.y / s4.y;
    rcG[((size_t)b * RR + 2) * NN + n] = e4.z / s4.z;
    rcG[((size_t)b * RR + 3) * NN + n] = e4.w / s4.w;

    // ---- scalar sums S_rp, S_uww ----
    const float prec_n = pprec[b * NN + n];
    float4 sp4, sw4;
    sp4.x = ur[0] * prec_n; sp4.y = ur[1] * prec_n; sp4.z = ur[2] * prec_n; sp4.w = ur[3] * prec_n;
    const float4 SrpV = block_sum4(sp4, red4, bc4);
    sw4.x = ur[0] * ww; sw4.y = ur[1] * ww; sw4.z = ur[2] * ww; sw4.w = ur[3] * ww;
    const float4 SuwwV = block_sum4(sw4, red4, bc4);
    if (tid == 0) {
        SrpG[b * RR + 0] = SrpV.x; SrpG[b * RR + 1] = SrpV.y;
        SrpG[b * RR + 2] = SrpV.z; SrpG[b * RR + 3] = SrpV.w;
        SuwwG[b * RR + 0] = SuwwV.x; SuwwG[b * RR + 1] = SuwwV.y;
        SuwwG[b * RR + 2] = SuwwV.z; SuwwG[b * RR + 3] = SuwwV.w;
    }
}

// ---------------- K2: one pass over prev_link (256 MB) ----------------
// R0's proven memory structure: grid (16, BB), block = 64 rows x full 1024 cols,
// 16 tiles of 64x64. rowU/rowV plain stores; colU/colV ONE 64-lane coalesced
// atomic instruction per wave per tile (R0's coalescing-verified form).
// New vs R0: u/uw row operands via wave-uniform GLOBAL loads (scalar K$ path,
// no LDS staging -> LDS 49KB->17.4KB, DS issue cut ~3x); col pass reads tile
// as b128 + shfl_xor(16,32) reduce (verified in R1) with col-side u held in
// registers; register double-buffer prefetch of the next tile.
__global__ __launch_bounds__(256, 4) void link_kernel(
    const float* __restrict__ L, const float* __restrict__ uG,
    const float* __restrict__ uwG,
    float* __restrict__ rowU, float* __restrict__ rowV,
    float* __restrict__ colU, float* __restrict__ colV)
{
    __shared__ float tile[64 * 68];    // pad 68: conflict-free b128 row & col reads

    const int b = blockIdx.y;
    const int n0 = blockIdx.x * 64;
    const int t = threadIdx.x;
    const int lane = t & 63;
    const int wid = t >> 6;            // = r (wave-uniform)
    const int widu = __builtin_amdgcn_readfirstlane(wid);   // force SGPR -> scalar loads

    const float* uR  = uG  + ((size_t)b * RR + widu) * NN;  // wave-uniform bases
    const float* uwR = uwG + ((size_t)b * RR + widu) * NN;

    // col-pass u values in registers: this lane covers rows n0 + q*16 + j, j=0..15
    const int q = lane >> 4;
    float4 ucol[4], uwcol[4];
#pragma unroll
    for (int j4 = 0; j4 < 4; ++j4) {
        ucol[j4]  = *(const float4*)(uR  + n0 + q * 16 + j4 * 4);
        uwcol[j4] = *(const float4*)(uwR + n0 + q * 16 + j4 * 4);
    }

    const float* Lb = L + (size_t)b * NN * NN + (size_t)n0 * NN;
    const int srow = t >> 4;           // staging rows: srow, +16, +32, +48
    const int sc4  = (t & 15) << 2;    // staging col (floats) within tile

    // prologue: tile 0 -> regs -> LDS
    float4 pre[4];
#pragma unroll
    for (int k = 0; k < 4; ++k)
        pre[k] = *(const float4*)&Lb[(size_t)(srow + (k << 4)) * NN + sc4];
#pragma unroll
    for (int k = 0; k < 4; ++k)
        *(float4*)&tile[(srow + (k << 4)) * 68 + sc4] = pre[k];

    float fuA = 0.f, fvA = 0.f;
    const int c16 = (lane & 15) << 2;

    for (int tt = 0; tt < 16; ++tt) {
        __syncthreads();               // tile tt visible
        if (tt < 15) {                 // prefetch next tile into regs
#pragma unroll
            for (int k = 0; k < 4; ++k)
                pre[k] = *(const float4*)&Lb[(size_t)(srow + (k << 4)) * NN + ((tt + 1) << 6) + sc4];
        }

        const int m0 = tt << 6;

        // ---- row pass: lane <-> row (n0+lane); u/uw wave-uniform from global ----
#pragma unroll
        for (int g = 0; g < 16; ++g) {
            const float4 v  = *(const float4*)&tile[lane * 68 + (g << 2)];
            const float4 u  = *(const float4*)(uR  + m0 + (g << 2));
            const float4 uw = *(const float4*)(uwR + m0 + (g << 2));
            fuA += v.x * u.x + v.y * u.y + v.z * u.z + v.w * u.w;
            fvA += v.x * uw.x + v.y * uw.y + v.z * uw.z + v.w * uw.w;
        }

        // ---- col pass: lane -> 4 cols (c16..c16+3), 16 rows of group q; b128 reads ----
        float4 cu4 = {0.f, 0.f, 0.f, 0.f}, cv4 = {0.f, 0.f, 0.f, 0.f};
#pragma unroll
        for (int j = 0; j < 16; ++j) {
            const int row = q * 16 + j;
            const float4 v = *(const float4*)&tile[row * 68 + c16];
            const float uv  = COMP4(ucol[j >> 2],  j & 3);   // static (j unrolled)
            const float uwv = COMP4(uwcol[j >> 2], j & 3);
            cu4.x += uv * v.x;  cu4.y += uv * v.y;  cu4.z += uv * v.z;  cu4.w += uv * v.w;
            cv4.x += uwv * v.x; cv4.y += uwv * v.y; cv4.z += uwv * v.z; cv4.w += uwv * v.w;
        }
        // merge the 4 q-groups (lanes differing in bits 4 and 5)
#pragma unroll
        for (int off = 16; off < 64; off <<= 1) {
            cu4.x += __shfl_xor(cu4.x, off, 64); cu4.y += __shfl_xor(cu4.y, off, 64);
            cu4.z += __shfl_xor(cu4.z, off, 64); cu4.w += __shfl_xor(cu4.w, off, 64);
            cv4.x += __shfl_xor(cv4.x, off, 64); cv4.y += __shfl_xor(cv4.y, off, 64);
            cv4.z += __shfl_xor(cv4.z, off, 64); cv4.w += __shfl_xor(cv4.w, off, 64);
        }
        // transpose: lane 'l' takes the scalar for column m0+l, then ONE 64-lane
        // coalesced atomic instruction per array (R0's proven pattern)
        {
            const int src = lane >> 2, cc = lane & 3;
            const float gx = __shfl(cu4.x, src, 64), gy = __shfl(cu4.y, src, 64);
            const float gz = __shfl(cu4.z, src, 64), gw = __shfl(cu4.w, src, 64);
            const float cuS = (cc == 0) ? gx : ((cc == 1) ? gy : ((cc == 2) ? gz : gw));
            const float hx = __shfl(cv4.x, src, 64), hy = __shfl(cv4.y, src, 64);
            const float hz = __shfl(cv4.z, src, 64), hw = __shfl(cv4.w, src, 64);
            const float cvS = (cc == 0) ? hx : ((cc == 1) ? hy : ((cc == 2) ? hz : hw));
            unsafeAtomicAdd(&colU[((size_t)b * RR + wid) * NN + m0 + lane], cuS);
            unsafeAtomicAdd(&colV[((size_t)b * RR + wid) * NN + m0 + lane], cvS);
        }

        __syncthreads();               // everyone done reading tile tt
        if (tt < 15) {
#pragma unroll
            for (int k = 0; k < 4; ++k)
                *(float4*)&tile[(srow + (k << 4)) * 68 + sc4] = pre[k];
        }
    }
    // full row sums owned by this block -> plain stores (no atomics, no memset)
    rowU[((size_t)b * RR + wid) * NN + n0 + lane] = fuA;
    rowV[((size_t)b * RR + wid) * NN + n0 + lane] = fvA;
}

// ---------------- K3: assemble read weights + read_words ----------------
// grid (16, BB): 64-row chunks; r folded into threads (t>>6) for phase 1.
__global__ __launch_bounds__(256) void combine_kernel(
    const float* __restrict__ memory, const float* __restrict__ prw,
    const float* __restrict__ pprec, const float* __restrict__ L,
    const float* __restrict__ evec_g, const float* __restrict__ wvec_g,
    const float* __restrict__ rmode_g,
    const float* __restrict__ wwG, const float* __restrict__ rcG,
    const float* __restrict__ rowU, const float* __restrict__ rowV,
    const float* __restrict__ colU, const float* __restrict__ colV,
    const float* __restrict__ SrpG, const float* __restrict__ SuwwG,
    float* __restrict__ out)
{
    __shared__ float rwL[RR][64];
    __shared__ float wwS[64];

    const int b = blockIdx.y;
    const int n0 = blockIdx.x * 64;
    const int t = threadIdx.x;
    const int r = t >> 6, i = t & 63;
    const int n = n0 + i;

    const float wwn = wwG[b * NN + n];
    if (r == 0) wwS[i] = wwn;
    const float prec_n = pprec[b * NN + n];
    const float diag = L[(size_t)b * NN * NN + (size_t)n * (NN + 1)];

    {
        const size_t idx = ((size_t)b * RR + r) * NN + n;
        const float un = prw[idx];
        const float rc = rcG[idx];
        const float ru = rowU[idx], rv = rowV[idx];
        const float cuv = colU[idx], cvv = colV[idx];
        const float Srp = SrpG[b * RR + r], Suww = SuwwG[b * RR + r];
        const float corr = un * (1.f - 2.f * wwn) * diag;
        const float fwd = (1.f - wwn) * ru - rv - corr + wwn * (Srp - un * prec_n);
        const float bwd = (1.f - wwn) * cuv - cvv - corr + prec_n * (Suww - un * wwn);
        const float m0 = rmode_g[((size_t)b * RR + r) * 3 + 0];
        const float m1 = rmode_g[((size_t)b * RR + r) * 3 + 1];
        const float m2 = rmode_g[((size_t)b * RR + r) * 3 + 2];
        const float mx = fmaxf(m0, fmaxf(m1, m2));
        const float e0 = expf(m0 - mx), e1 = expf(m1 - mx), e2 = expf(m2 - mx);
        const float inv = 1.f / (e0 + e1 + e2);
        // mode[...,0]=backward, [...,1]=forward, [...,2]=content
        rwL[r][i] = (e2 * inv) * rc + (e1 * inv) * fwd + (e0 * inv) * bwd;
    }
    __syncthreads();

    // partial read_words over this 64-row chunk; wave r handles read head r, lane = w
    const int w = i;
    const float ev = evec_g[b * WD + w], wv = wvec_g[b * WD + w];
    float acc = 0.f;
    const float* mb = memory + ((size_t)b * NN + n0) * WD;
#pragma unroll 8
    for (int k = 0; k < 64; ++k) {
        const float m = mb[(size_t)k * WD + w];
        const float wwi = wwS[k];
        acc += rwL[r][k] * (m * (1.f - wwi * ev) + wwi * wv);
    }
    unsafeAtomicAdd(&out[((size_t)b * RR + r) * WD + w], acc);
}

// ---------------- launch ----------------
extern "C" void kernel_launch(void* const* d_in, const int* in_sizes, int n_in,
                              void* d_out, int out_size, void* d_ws, size_t ws_size,
                              hipStream_t stream) {
    const float* memory = (const float*)d_in[0];
    const float* prw    = (const float*)d_in[1];
    const float* pww    = (const float*)d_in[2];
    const float* pusage = (const float*)d_in[3];
    const float* plink  = (const float*)d_in[4];
    const float* pprec  = (const float*)d_in[5];
    const float* rkeys  = (const float*)d_in[6];
    const float* rstr   = (const float*)d_in[7];
    const float* wkeys  = (const float*)d_in[8];
    const float* wstr   = (const float*)d_in[9];
    const float* wvec   = (const float*)d_in[10];
    const float* evec   = (const float*)d_in[11];
    const float* fg     = (const float*)d_in[12];
    const float* ag     = (const float*)d_in[13];
    const float* wg     = (const float*)d_in[14];
    const float* rmode  = (const float*)d_in[15];

    float* ws = (float*)d_ws;
    const size_t BN  = (size_t)BB * NN;          // 65536
    const size_t BRN = (size_t)BB * RR * NN;     // 262144
    float* wwG  = ws;
    float* rcG  = wwG + BN;
    float* uwG  = rcG + BRN;
    float* rowU = uwG + BRN;
    float* rowV = rowU + BRN;
    float* colU = rowV + BRN;
    float* colV = colU + BRN;
    float* Srp  = colV + BRN;
    float* Suww = Srp + (size_t)BB * RR;

    // zero the atomic accumulators (colU,colV contiguous) and output
    hipMemsetAsync(colU, 0, 2 * BRN * sizeof(float), stream);
    hipMemsetAsync(d_out, 0, (size_t)out_size * sizeof(float), stream);

    prep_kernel<<<BB, 1024, 0, stream>>>(memory, prw, pww, pusage, pprec,
                                         rkeys, rstr, wkeys, wstr, wvec, evec,
                                         fg, ag, wg, wwG, uwG, rcG, Srp, Suww);
    link_kernel<<<dim3(16, BB), 256, 0, stream>>>(plink, prw, uwG,
                                                  rowU, rowV, colU, colV);
    combine_kernel<<<dim3(16, BB), 256, 0, stream>>>(memory, prw, pprec, plink,
                                                     evec, wvec, rmode,
                                                     wwG, rcG, rowU, rowV, colU, colV,
                                                     Srp, Suww, (float*)d_out);
}